// Round 8
// baseline (126.410 us; speedup 1.0000x reference)
//
#include <hip/hip_runtime.h>
#include <hip/hip_fp16.h>

#define D 50
#define HIDDEN 32
#define NPB 128        // nodes per block in node_proj
#define ZPAD 52        // padded LDS row stride (words); 208 B, 16B-aligned
#define WROW 64        // W1T row stride in floats (256 B)

// ---------------------------------------------------------------------------
// Kernel 0: build W1T[64][WROW]:  row j, k<50 -> weight for output col j,
// k==50 -> bias (b1[j] for j<32, 0 for dst half), else 0.
//   j<32 : W1T[j][k] = W1[k][j]        (src half, + b1[j] at slot 50)
//   j>=32: W1T[j][k] = W1[50+k][j-32]  (dst half)
// 16 KB total -> stays resident in the per-CU scalar cache during kernel 1.
// ---------------------------------------------------------------------------
__global__ void build_w1t_kernel(const float* __restrict__ W1,
                                 const float* __restrict__ b1,
                                 float* __restrict__ W1T) {
    int i = blockIdx.x * blockDim.x + threadIdx.x;
    if (i >= 64 * WROW) return;
    int j = i >> 6;            // output column 0..63
    int k = i & (WROW - 1);    // 0..63
    float v = 0.0f;
    if (k < D) {
        v = (j < 32) ? W1[(size_t)k * HIDDEN + j]
                     : W1[(size_t)(D + k) * HIDDEN + (j - 32)];
    } else if (k == D) {
        v = (j < 32) ? b1[j] : 0.0f;
    }
    W1T[i] = v;
}

// ---------------------------------------------------------------------------
// Kernel 1: per-node projections -> fp16 table P[n][64].
// TRANSPOSED decomposition: one LANE per node. The per-node z row lives in
// 50 VGPRs (staged coalesced through LDS: 13 ds_read_b128 per 64 NODES,
// vs 13 per node in the broadcast scheme -- the LDS pipe was the 24us floor).
// The shared operand is now W1T (16 KB, K$-resident): w[k] is wave-uniform ->
// s_load batches on the scalar cache, consumed directly by v_fma.
// Wave pairs split the 32 column-pairs (jp 0..15 / 16..31) to double the
// wave count for latency hiding. Store: packed __half2 per column pair.
// ---------------------------------------------------------------------------
__global__ __launch_bounds__(256, 2) void node_proj_kernel(
        const float* __restrict__ z,
        const float* __restrict__ W1T,
        __half2* __restrict__ P2,      // P viewed as half2[n_nodes][32]
        int n_nodes) {
    __shared__ __align__(16) float zs[NPB * ZPAD];   // 26.6 KB

    const int tid  = threadIdx.x;
    const int base = blockIdx.x * NPB;
    int nloc = n_nodes - base;
    if (nloc > NPB) nloc = NPB;

    // ---- stage z rows coalesced (float2 -> padded LDS rows) ----
    const float2* src2 = (const float2*)(z + (size_t)base * D);
    const int nf2 = nloc * (D / 2);
    for (int i = tid; i < nf2; i += 256) {
        int row = i / 25;
        int c   = i - row * 25;
        *(float2*)(zs + row * ZPAD + 2 * c) = src2[i];
    }
    __syncthreads();

    const int lane  = tid & 63;
    const int wv    = tid >> 6;          // 0..3
    const int grp   = wv & 1;            // node group within block
    const int jbase = (wv >> 1) * 16;    // column-pair range: 0..15 or 16..31
    const int nl    = grp * 64 + lane;   // local node index
    const int node  = base + nl;
    const bool act  = (node < n_nodes) && (nl < nloc);

    // ---- own z row -> 50 VGPRs (12x b128 + 1x b64, 16B-aligned stride) ----
    float zr[D];
    const float4* row4 = (const float4*)(zs + nl * ZPAD);
#pragma unroll
    for (int q = 0; q < 12; ++q) {
        float4 v = row4[q];
        zr[4 * q]     = v.x;
        zr[4 * q + 1] = v.y;
        zr[4 * q + 2] = v.z;
        zr[4 * q + 3] = v.w;
    }
    {
        float2 t = *(const float2*)(zs + nl * ZPAD + 48);
        zr[48] = t.x;
        zr[49] = t.y;
    }

    // ---- 16 column pairs: two uniform W1T rows per iteration ----
    for (int jp = jbase; jp < jbase + 16; ++jp) {
        const float* w0 = W1T + (size_t)(2 * jp) * WROW;
        const float* w1 = W1T + (size_t)(2 * jp + 1) * WROW;
        float a0 = w0[D];                // bias slot
        float a1 = w1[D];
#pragma unroll
        for (int k = 0; k < D; ++k) {
            a0 = fmaf(zr[k], w0[k], a0); // w0[k]: wave-uniform -> SGPR operand
            a1 = fmaf(zr[k], w1[k], a1);
        }
        if (act) {
            P2[(size_t)node * 32 + jp] = __floats2half2_rn(a0, a1);
        }
    }
}

// ---------------------------------------------------------------------------
// Kernel 2: per-edge fused add + relu + dot(W2) + b2 -- 4 lanes per edge
// (round-5 proven form: 52 us, byte-bound on the random-gather fabric path;
// transaction-cut and ILP experiments were both null).
// ---------------------------------------------------------------------------
__global__ void edge_mlp_kernel(const int* __restrict__ eidx,
                                const __half* __restrict__ P,
                                const float* __restrict__ W2,
                                const float* __restrict__ b2,
                                float* __restrict__ out,
                                int n_edges) {
    int t = blockIdx.x * blockDim.x + threadIdx.x;
    int e = t >> 2;
    int r = t & 3;
    if (e >= n_edges) return;

    int s = eidx[e];
    int d = eidx[n_edges + e];

    uint4 ua = *(const uint4*)(P + (size_t)s * 64 + r * 8);
    uint4 ub = *(const uint4*)(P + (size_t)d * 64 + 32 + r * 8);
    float4 w0 = *(const float4*)(W2 + r * 8);
    float4 w1 = *(const float4*)(W2 + r * 8 + 4);

    float2 a0 = __half22float2(*(const __half2*)&ua.x);
    float2 a1 = __half22float2(*(const __half2*)&ua.y);
    float2 a2 = __half22float2(*(const __half2*)&ua.z);
    float2 a3 = __half22float2(*(const __half2*)&ua.w);
    float2 b0 = __half22float2(*(const __half2*)&ub.x);
    float2 b1v = __half22float2(*(const __half2*)&ub.y);
    float2 b2v = __half22float2(*(const __half2*)&ub.z);
    float2 b3 = __half22float2(*(const __half2*)&ub.w);

    float acc = (r == 0) ? b2[0] : 0.0f;
    acc = fmaf(fmaxf(a0.x + b0.x,  0.0f), w0.x, acc);
    acc = fmaf(fmaxf(a0.y + b0.y,  0.0f), w0.y, acc);
    acc = fmaf(fmaxf(a1.x + b1v.x, 0.0f), w0.z, acc);
    acc = fmaf(fmaxf(a1.y + b1v.y, 0.0f), w0.w, acc);
    acc = fmaf(fmaxf(a2.x + b2v.x, 0.0f), w1.x, acc);
    acc = fmaf(fmaxf(a2.y + b2v.y, 0.0f), w1.y, acc);
    acc = fmaf(fmaxf(a3.x + b3.x,  0.0f), w1.z, acc);
    acc = fmaf(fmaxf(a3.y + b3.y,  0.0f), w1.w, acc);

    acc += __shfl_xor(acc, 1);
    acc += __shfl_xor(acc, 2);

    if (r == 0) out[e] = acc;
}

// ---------------------------------------------------------------------------
// Fallback (ws too small): direct per-edge full MLP. Slow but correct.
// ---------------------------------------------------------------------------
__global__ void edge_direct_kernel(const float* __restrict__ z,
                                   const int* __restrict__ eidx,
                                   const float* __restrict__ W1,
                                   const float* __restrict__ b1,
                                   const float* __restrict__ W2,
                                   const float* __restrict__ b2,
                                   float* __restrict__ out,
                                   int n_edges) {
    int e = blockIdx.x * blockDim.x + threadIdx.x;
    if (e >= n_edges) return;
    int s = eidx[e];
    int d = eidx[n_edges + e];
    const float* zs = z + (size_t)s * D;
    const float* zd = z + (size_t)d * D;
    float acc = b2[0];
    for (int j = 0; j < HIDDEN; ++j) {
        float h = b1[j];
        for (int k = 0; k < D; ++k) {
            h = fmaf(zs[k], W1[(size_t)k * HIDDEN + j], h);
            h = fmaf(zd[k], W1[(size_t)(D + k) * HIDDEN + j], h);
        }
        acc = fmaf(fmaxf(h, 0.0f), W2[j], acc);
    }
    out[e] = acc;
}

extern "C" void kernel_launch(void* const* d_in, const int* in_sizes, int n_in,
                              void* d_out, int out_size, void* d_ws, size_t ws_size,
                              hipStream_t stream) {
    const float* z    = (const float*)d_in[0];
    const int*   eidx = (const int*)d_in[1];
    const float* W1   = (const float*)d_in[2];
    const float* b1   = (const float*)d_in[3];
    const float* W2   = (const float*)d_in[4];
    const float* b2   = (const float*)d_in[5];
    float*       out  = (float*)d_out;

    const int n_nodes = in_sizes[0] / D;          // 100000
    const int n_edges = in_sizes[1] / 2;          // 2000000

    const size_t p_bytes   = (size_t)n_nodes * 64 * sizeof(__half);
    const size_t w1t_bytes = (size_t)64 * WROW * sizeof(float);   // 16 KB

    if (p_bytes + w1t_bytes <= ws_size) {
        __half* P   = (__half*)d_ws;
        float*  W1T = (float*)((char*)d_ws + p_bytes);

        // Kernel 0: build the 16 KB transposed weight table.
        build_w1t_kernel<<<(64 * WROW + 255) / 256, 256, 0, stream>>>(W1, b1, W1T);

        // Kernel 1: one lane per node; 128 nodes per 256-thread block.
        int blocks1 = (n_nodes + NPB - 1) / NPB;
        node_proj_kernel<<<blocks1, 256, 0, stream>>>(z, W1T, (__half2*)P,
                                                      n_nodes);

        // Kernel 2: 4 threads per edge.
        long long total2 = (long long)n_edges * 4;
        int blocks2 = (int)((total2 + 255) / 256);
        edge_mlp_kernel<<<blocks2, 256, 0, stream>>>(eidx, P, W2, b2, out, n_edges);
    } else {
        int blocks = (n_edges + 255) / 256;
        edge_direct_kernel<<<blocks, 256, 0, stream>>>(z, eidx, W1, b1, W2, b2,
                                                       out, n_edges);
    }
}

// Round 9
// 71.404 us; speedup vs baseline: 1.7703x; 1.7703x over previous
//
#include <hip/hip_runtime.h>
#include <hip/hip_fp16.h>

#define D 50
#define HIDDEN 32
#define TPW 2          // 16-node tiles per wave in node_proj

using short8 = __attribute__((ext_vector_type(8))) short;   // 8 bf16 (4 VGPRs)
using f32x4  = __attribute__((ext_vector_type(4))) float;   // acc

// f32 -> bf16 bits, round-nearest-even (normal values; inputs are tame).
static __device__ __forceinline__ short bfbits(float f) {
    unsigned u = __float_as_uint(f);
    unsigned r = (u + 0x7FFFu + ((u >> 16) & 1u)) >> 16;
    return (short)r;
}

// ---------------------------------------------------------------------------
// Kernel 0: pack W1^T (+bias row) into MFMA B-fragment order, bf16.
// Logical B[64][64]: B[k][j] = W1[k][j] (j<32) / W1[50+k][j-32] (j>=32) for
// k<50; B[50][j] = b1[j] (j<32) else 0; B[k>50][*] = 0.
// Fragment f = jt*2 + ks (jt = 16-col tile, ks = K-step). Lane l, elem e maps
// to B[ks*32 + (l>>4)*8 + e][jt*16 + (l&15)]. Stored so the node kernel does
// ONE coalesced 16B load per lane per fragment. 8 KB total -> L2-resident.
// ---------------------------------------------------------------------------
__global__ void build_w1tb_kernel(const float* __restrict__ W1,
                                  const float* __restrict__ b1,
                                  short* __restrict__ W1TB) {
    int idx = blockIdx.x * blockDim.x + threadIdx.x;
    if (idx >= 512) return;
    int f  = idx >> 6;          // fragment 0..7
    int l  = idx & 63;          // lane
    int jt = f >> 1, ks = f & 1;
    int kg = l >> 4,  c = l & 15;
    int j  = jt * 16 + c;

    short v[8];
#pragma unroll
    for (int e = 0; e < 8; ++e) {
        int k = ks * 32 + kg * 8 + e;
        float x = 0.0f;
        if (k < D)       x = (j < 32) ? W1[(size_t)k * HIDDEN + j]
                                      : W1[(size_t)(D + k) * HIDDEN + (j - 32)];
        else if (k == D) x = (j < 32) ? b1[j] : 0.0f;
        v[e] = bfbits(x);
    }
    // Pack to one int4 (16B store, 16B-aligned: (f*512 + l*8)*2B).
    int4 o;
    o.x = (v[1] << 16) | (v[0] & 0xffff);
    o.y = (v[3] << 16) | (v[2] & 0xffff);
    o.z = (v[5] << 16) | (v[4] & 0xffff);
    o.w = (v[7] << 16) | (v[6] & 0xffff);
    *(int4*)(W1TB + (size_t)f * 512 + l * 8) = o;
}

// ---------------------------------------------------------------------------
// Kernel 1: node projections via MFMA -> fp16 table P[n][64].
// GEMM [n_nodes x 64pad] @ [64pad x 64]; A = z rows (k=50 slot = 1.0 for the
// bias, rest zero-pad), B = W1TB fragments. Per wave-tile (16 nodes):
// A-frags straight from global z (8B-aligned float2, no LDS/barrier),
// 8 MFMA (4 col-tiles x 2 K-steps), C/D layout col=lane&15,
// row=(lane>>4)*4+reg. Operand reuse happens inside the matrix unit --
// this sidesteps the ~25us per-CU broadcast-pipe floor of all VALU schemes.
// ---------------------------------------------------------------------------
__global__ __launch_bounds__(256) void node_proj_mfma_kernel(
        const float* __restrict__ z,
        const short* __restrict__ W1TB,
        __half2* __restrict__ P2,      // P viewed as half2[n_nodes][32]
        int n_nodes) {
    const int lane = threadIdx.x & 63;
    const int wid  = (blockIdx.x * blockDim.x + threadIdx.x) >> 6;
    const int kg   = lane >> 4;        // K-group 0..3
    const int c    = lane & 15;        // col-in-tile / row-in-tile

    // B fragments: 8 coalesced 16B loads (L2-hot, shared by all waves).
    short8 bf[8];
#pragma unroll
    for (int f = 0; f < 8; ++f)
        bf[f] = *(const short8*)(W1TB + (size_t)f * 512 + lane * 8);

    for (int t = 0; t < TPW; ++t) {
        int tile = wid * TPW + t;
        int nb   = tile * 16;
        if (nb >= n_nodes) return;

        int  rown = nb + c;
        bool rv   = rown < n_nodes;
        const float* zrow = z + (size_t)(rv ? rown : 0) * D;

        // ---- A fragments: k = kg*8+e (step 0), 32+kg*8+e (step 1) ----
        float za[8], zb[8];
        {
            const float2* p = (const float2*)(zrow + kg * 8);   // k<=31 valid
            float2 q0 = p[0], q1 = p[1], q2 = p[2], q3 = p[3];
            za[0] = q0.x; za[1] = q0.y; za[2] = q1.x; za[3] = q1.y;
            za[4] = q2.x; za[5] = q2.y; za[6] = q3.x; za[7] = q3.y;
        }
        if (kg < 2) {                                           // k 32..47
            const float2* p = (const float2*)(zrow + 32 + kg * 8);
            float2 q0 = p[0], q1 = p[1], q2 = p[2], q3 = p[3];
            zb[0] = q0.x; zb[1] = q0.y; zb[2] = q1.x; zb[3] = q1.y;
            zb[4] = q2.x; zb[5] = q2.y; zb[6] = q3.x; zb[7] = q3.y;
        } else if (kg == 2) {                                   // k 48..55
            float2 q0 = *(const float2*)(zrow + 48);
            zb[0] = q0.x; zb[1] = q0.y;
            zb[2] = 1.0f;                                       // bias slot k=50
            zb[3] = zb[4] = zb[5] = zb[6] = zb[7] = 0.0f;
        } else {                                                // k 56..63
#pragma unroll
            for (int e = 0; e < 8; ++e) zb[e] = 0.0f;
        }

        short8 a0, a1;
#pragma unroll
        for (int e = 0; e < 8; ++e) { a0[e] = bfbits(za[e]); a1[e] = bfbits(zb[e]); }

        // ---- 4 col-tiles x (2 MFMA + packed store) ----
#pragma unroll
        for (int jt = 0; jt < 4; ++jt) {
            f32x4 acc = {0.0f, 0.0f, 0.0f, 0.0f};
            acc = __builtin_amdgcn_mfma_f32_16x16x32_bf16(a0, bf[jt * 2],     acc, 0, 0, 0);
            acc = __builtin_amdgcn_mfma_f32_16x16x32_bf16(a1, bf[jt * 2 + 1], acc, 0, 0, 0);
#pragma unroll
            for (int r = 0; r < 4; ++r) {
                float v0 = acc[r];
                float v1 = __shfl_xor(v0, 1);        // col partner
                int node = nb + kg * 4 + r;          // D row = (lane>>4)*4 + r
                if (((lane & 1) == 0) && node < n_nodes) {
                    P2[(size_t)node * 32 + jt * 8 + (c >> 1)] =
                        __floats2half2_rn(v0, v1);
                }
            }
        }
    }
}

// ---------------------------------------------------------------------------
// Kernel 2: per-edge fused add + relu + dot(W2) + b2 -- 4 lanes per edge
// (round-5 proven form: 52 us, byte-bound on the random-gather fabric path;
// transaction-cut and ILP experiments were both null).
// ---------------------------------------------------------------------------
__global__ void edge_mlp_kernel(const int* __restrict__ eidx,
                                const __half* __restrict__ P,
                                const float* __restrict__ W2,
                                const float* __restrict__ b2,
                                float* __restrict__ out,
                                int n_edges) {
    int t = blockIdx.x * blockDim.x + threadIdx.x;
    int e = t >> 2;
    int r = t & 3;
    if (e >= n_edges) return;

    int s = eidx[e];
    int d = eidx[n_edges + e];

    uint4 ua = *(const uint4*)(P + (size_t)s * 64 + r * 8);
    uint4 ub = *(const uint4*)(P + (size_t)d * 64 + 32 + r * 8);
    float4 w0 = *(const float4*)(W2 + r * 8);
    float4 w1 = *(const float4*)(W2 + r * 8 + 4);

    float2 a0 = __half22float2(*(const __half2*)&ua.x);
    float2 a1 = __half22float2(*(const __half2*)&ua.y);
    float2 a2 = __half22float2(*(const __half2*)&ua.z);
    float2 a3 = __half22float2(*(const __half2*)&ua.w);
    float2 b0 = __half22float2(*(const __half2*)&ub.x);
    float2 b1v = __half22float2(*(const __half2*)&ub.y);
    float2 b2v = __half22float2(*(const __half2*)&ub.z);
    float2 b3 = __half22float2(*(const __half2*)&ub.w);

    float acc = (r == 0) ? b2[0] : 0.0f;
    acc = fmaf(fmaxf(a0.x + b0.x,  0.0f), w0.x, acc);
    acc = fmaf(fmaxf(a0.y + b0.y,  0.0f), w0.y, acc);
    acc = fmaf(fmaxf(a1.x + b1v.x, 0.0f), w0.z, acc);
    acc = fmaf(fmaxf(a1.y + b1v.y, 0.0f), w0.w, acc);
    acc = fmaf(fmaxf(a2.x + b2v.x, 0.0f), w1.x, acc);
    acc = fmaf(fmaxf(a2.y + b2v.y, 0.0f), w1.y, acc);
    acc = fmaf(fmaxf(a3.x + b3.x,  0.0f), w1.z, acc);
    acc = fmaf(fmaxf(a3.y + b3.y,  0.0f), w1.w, acc);

    acc += __shfl_xor(acc, 1);
    acc += __shfl_xor(acc, 2);

    if (r == 0) out[e] = acc;
}

// ---------------------------------------------------------------------------
// Fallback (ws too small): direct per-edge full MLP. Slow but correct.
// ---------------------------------------------------------------------------
__global__ void edge_direct_kernel(const float* __restrict__ z,
                                   const int* __restrict__ eidx,
                                   const float* __restrict__ W1,
                                   const float* __restrict__ b1,
                                   const float* __restrict__ W2,
                                   const float* __restrict__ b2,
                                   float* __restrict__ out,
                                   int n_edges) {
    int e = blockIdx.x * blockDim.x + threadIdx.x;
    if (e >= n_edges) return;
    int s = eidx[e];
    int d = eidx[n_edges + e];
    const float* zs = z + (size_t)s * D;
    const float* zd = z + (size_t)d * D;
    float acc = b2[0];
    for (int j = 0; j < HIDDEN; ++j) {
        float h = b1[j];
        for (int k = 0; k < D; ++k) {
            h = fmaf(zs[k], W1[(size_t)k * HIDDEN + j], h);
            h = fmaf(zd[k], W1[(size_t)(D + k) * HIDDEN + j], h);
        }
        acc = fmaf(fmaxf(h, 0.0f), W2[j], acc);
    }
    out[e] = acc;
}

extern "C" void kernel_launch(void* const* d_in, const int* in_sizes, int n_in,
                              void* d_out, int out_size, void* d_ws, size_t ws_size,
                              hipStream_t stream) {
    const float* z    = (const float*)d_in[0];
    const int*   eidx = (const int*)d_in[1];
    const float* W1   = (const float*)d_in[2];
    const float* b1   = (const float*)d_in[3];
    const float* W2   = (const float*)d_in[4];
    const float* b2   = (const float*)d_in[5];
    float*       out  = (float*)d_out;

    const int n_nodes = in_sizes[0] / D;          // 100000
    const int n_edges = in_sizes[1] / 2;          // 2000000

    const size_t p_bytes = (size_t)n_nodes * 64 * sizeof(__half);
    const size_t w_bytes = (size_t)8 * 512 * sizeof(short);       // 8 KB

    if (p_bytes + w_bytes <= ws_size) {
        __half* P    = (__half*)d_ws;
        short*  W1TB = (short*)((char*)d_ws + p_bytes);

        // Kernel 0: fragment-ordered bf16 weight table (8 KB).
        build_w1tb_kernel<<<2, 256, 0, stream>>>(W1, b1, W1TB);

        // Kernel 1: MFMA projections; one wave per TPW 16-node tiles.
        int tiles   = (n_nodes + 15) / 16;
        int waves   = (tiles + TPW - 1) / TPW;
        int blocks1 = (waves * 64 + 255) / 256;
        node_proj_mfma_kernel<<<blocks1, 256, 0, stream>>>(z, W1TB, (__half2*)P,
                                                           n_nodes);

        // Kernel 2: 4 threads per edge.
        long long total2 = (long long)n_edges * 4;
        int blocks2 = (int)((total2 + 255) / 256);
        edge_mlp_kernel<<<blocks2, 256, 0, stream>>>(eidx, P, W2, b2, out, n_edges);
    } else {
        int blocks = (n_edges + 255) / 256;
        edge_direct_kernel<<<blocks, 256, 0, stream>>>(z, eidx, W1, b1, W2, b2,
                                                       out, n_edges);
    }
}